// Round 10
// baseline (14634.183 us; speedup 1.0000x reference)
//
#include <hip/hip_runtime.h>
#include <hip/hip_bf16.h>
#include <math.h>

// Problem constants
#define SEQ   2048
#define VOC   50257
#define EMB   512
#define HID   768
#define G3    2304      // 3*HID
#define MDIM  256
#define CSZ   64
#define NCHUNK 32
#define UDIM  2048
#define E4    2048      // 4*EMB

#define G_GRU 48             // fallback-path GRU WGs
#define NROLE 32             // clustered-path roles (24 units each)
#define CANARY 0xFFFFFFFFu   // -NaN; GRU h is always finite => unreachable

typedef uint32_t u32x4  __attribute__((ext_vector_type(4)));
typedef float    f32x4  __attribute__((ext_vector_type(4)));
typedef short    s16x8  __attribute__((ext_vector_type(8)));   // 8 bf16 (4 VGPRs)
typedef __bf16   bf16x8 __attribute__((ext_vector_type(8)));

// ---------------------------------------------------------------------------
// fp32 -> bf16 convert (grid-stride, 8 elems/thread)
// ---------------------------------------------------------------------------
__global__ __launch_bounds__(256) void cvt_f32_bf16(const float* __restrict__ src,
                                                    __bf16* __restrict__ dst, int n8) {
    int stride = gridDim.x * 256;
    for (int i = blockIdx.x * 256 + threadIdx.x; i < n8; i += stride) {
        const float4* s = reinterpret_cast<const float4*>(src + (size_t)i * 8);
        float4 a = s[0], b = s[1];
        bf16x8 o;
        o[0]=(__bf16)a.x; o[1]=(__bf16)a.y; o[2]=(__bf16)a.z; o[3]=(__bf16)a.w;
        o[4]=(__bf16)b.x; o[5]=(__bf16)b.y; o[6]=(__bf16)b.z; o[7]=(__bf16)b.w;
        *reinterpret_cast<bf16x8*>(dst + (size_t)i * 8) = o;
    }
}

// ---------------------------------------------------------------------------
// Embedding gathers
// ---------------------------------------------------------------------------
__global__ __launch_bounds__(256) void embed_kernel(const int* __restrict__ ids,
                                                    const float* __restrict__ emb,
                                                    float* __restrict__ X) {
    int s = blockIdx.x;
    int id = ids[s];
    const float* src = &emb[(size_t)id * EMB];
    float* dst = &X[(size_t)s * EMB];
    for (int i = threadIdx.x; i < EMB; i += 256) dst[i] = src[i];
}

// gather + convert from fp32 emb directly (keeps emb16 cvt off pre-GRU path)
__global__ __launch_bounds__(64) void embed16c_kernel(const int* __restrict__ ids,
                                                      const float* __restrict__ emb,
                                                      __bf16* __restrict__ X16) {
    int s = blockIdx.x;
    int id = ids[s];
    const float4* src = reinterpret_cast<const float4*>(emb + (size_t)id * EMB);
    int i = threadIdx.x;              // 64 threads x 8 floats = 512
    float4 a = src[i * 2], b = src[i * 2 + 1];
    bf16x8 o;
    o[0]=(__bf16)a.x; o[1]=(__bf16)a.y; o[2]=(__bf16)a.z; o[3]=(__bf16)a.w;
    o[4]=(__bf16)b.x; o[5]=(__bf16)b.y; o[6]=(__bf16)b.z; o[7]=(__bf16)b.w;
    reinterpret_cast<bf16x8*>(X16 + (size_t)s * EMB)[i] = o;
}

// ---------------------------------------------------------------------------
// Generic fp32 GEMM (128x128, BK=16). EPI 1 = relu^2.
// ---------------------------------------------------------------------------
template<int EPI>
__global__ __launch_bounds__(256) void gemm_nt(const float* __restrict__ A,
                                               const float* __restrict__ B,
                                               const float* __restrict__ bias,
                                               float* __restrict__ C,
                                               int M, int N, int K) {
    __shared__ float As[16][132];
    __shared__ float Bs[16][132];
    const int tid = threadIdx.x;
    const int tx = tid & 15;
    const int ty = tid >> 4;
    const int m0 = blockIdx.y * 128;
    const int n0 = blockIdx.x * 128;

    float acc[8][8];
    #pragma unroll
    for (int i = 0; i < 8; i++)
        #pragma unroll
        for (int j = 0; j < 8; j++) acc[i][j] = 0.f;

    for (int k0 = 0; k0 < K; k0 += 16) {
        #pragma unroll
        for (int i = 0; i < 2; i++) {
            int idx = tid * 2 + i;
            int r   = idx >> 2;
            int c4  = idx & 3;
            float4 av = {0.f, 0.f, 0.f, 0.f};
            float4 bv = {0.f, 0.f, 0.f, 0.f};
            int ar = m0 + r;
            if (ar < M) av = *reinterpret_cast<const float4*>(&A[(size_t)ar * K + k0 + c4 * 4]);
            int br = n0 + r;
            if (br < N) bv = *reinterpret_cast<const float4*>(&B[(size_t)br * K + k0 + c4 * 4]);
            As[c4 * 4 + 0][r] = av.x; As[c4 * 4 + 1][r] = av.y;
            As[c4 * 4 + 2][r] = av.z; As[c4 * 4 + 3][r] = av.w;
            Bs[c4 * 4 + 0][r] = bv.x; Bs[c4 * 4 + 1][r] = bv.y;
            Bs[c4 * 4 + 2][r] = bv.z; Bs[c4 * 4 + 3][r] = bv.w;
        }
        __syncthreads();
        #pragma unroll
        for (int k = 0; k < 16; k++) {
            float4 a0 = *reinterpret_cast<const float4*>(&As[k][ty * 4]);
            float4 a1 = *reinterpret_cast<const float4*>(&As[k][64 + ty * 4]);
            float4 b0 = *reinterpret_cast<const float4*>(&Bs[k][tx * 4]);
            float4 b1 = *reinterpret_cast<const float4*>(&Bs[k][64 + tx * 4]);
            float a[8] = {a0.x, a0.y, a0.z, a0.w, a1.x, a1.y, a1.z, a1.w};
            float b[8] = {b0.x, b0.y, b0.z, b0.w, b1.x, b1.y, b1.z, b1.w};
            #pragma unroll
            for (int i = 0; i < 8; i++)
                #pragma unroll
                for (int j = 0; j < 8; j++)
                    acc[i][j] = fmaf(a[i], b[j], acc[i][j]);
        }
        __syncthreads();
    }

    #pragma unroll
    for (int i = 0; i < 8; i++) {
        int r = m0 + ((i < 4) ? (ty * 4 + i) : (64 + ty * 4 + (i - 4)));
        if (r >= M) continue;
        #pragma unroll
        for (int j = 0; j < 8; j++) {
            int c = n0 + ((j < 4) ? (tx * 4 + j) : (64 + tx * 4 + (j - 4)));
            if (c >= N) continue;
            float v = acc[i][j] + bias[c];
            if (EPI == 1) { v = fmaxf(v, 0.f); v = v * v; }
            C[(size_t)r * N + c] = v;
        }
    }
}

// ---------------------------------------------------------------------------
// Device MFMA tile: C[128 x 128] at (m0,n0) = A @ B^T + bias.
// (all four template variants numerically verified in rounds 3-9)
// ---------------------------------------------------------------------------
template<bool A16, bool B16, int EPI, bool OUT16>
__device__ void mfma_tile(const void* Ap, const void* Bp,
                          const float* __restrict__ bias, void* Cp,
                          int m0, int n0, int N, int K,
                          __bf16* As, __bf16* Bs) {
    constexpr int LDT = 40;
    const int tid  = threadIdx.x;
    const int lane = tid & 63;
    const int wave = tid >> 6;
    const int wm = wave >> 1, wn = wave & 1;
    const int l15 = lane & 15, l4 = lane >> 4;
    const int r = tid >> 1, hf = tid & 1;

    f32x4 acc[4][4];
    #pragma unroll
    for (int i = 0; i < 4; i++)
        #pragma unroll
        for (int j = 0; j < 4; j++) acc[i][j] = (f32x4){0.f, 0.f, 0.f, 0.f};

    for (int k0 = 0; k0 < K; k0 += 32) {
        s16x8 av0, av1, bv0, bv1;
        if constexpr (A16) {
            const __bf16* ap = (const __bf16*)Ap + (size_t)(m0 + r) * K + k0 + hf * 16;
            av0 = *reinterpret_cast<const s16x8*>(ap);
            av1 = *reinterpret_cast<const s16x8*>(ap + 8);
        } else {
            const float* ap = (const float*)Ap + (size_t)(m0 + r) * K + k0 + hf * 16;
            float4 a0 = *reinterpret_cast<const float4*>(ap);
            float4 a1 = *reinterpret_cast<const float4*>(ap + 4);
            float4 a2 = *reinterpret_cast<const float4*>(ap + 8);
            float4 a3 = *reinterpret_cast<const float4*>(ap + 12);
            bf16x8 w0, w1;
            w0[0]=(__bf16)a0.x; w0[1]=(__bf16)a0.y; w0[2]=(__bf16)a0.z; w0[3]=(__bf16)a0.w;
            w0[4]=(__bf16)a1.x; w0[5]=(__bf16)a1.y; w0[6]=(__bf16)a1.z; w0[7]=(__bf16)a1.w;
            w1[0]=(__bf16)a2.x; w1[1]=(__bf16)a2.y; w1[2]=(__bf16)a2.z; w1[3]=(__bf16)a2.w;
            w1[4]=(__bf16)a3.x; w1[5]=(__bf16)a3.y; w1[6]=(__bf16)a3.z; w1[7]=(__bf16)a3.w;
            av0 = __builtin_bit_cast(s16x8, w0); av1 = __builtin_bit_cast(s16x8, w1);
        }
        int bn = n0 + r;
        if constexpr (B16) {
            if (bn < N) {
                const __bf16* bp2 = (const __bf16*)Bp + (size_t)bn * K + k0 + hf * 16;
                bv0 = *reinterpret_cast<const s16x8*>(bp2);
                bv1 = *reinterpret_cast<const s16x8*>(bp2 + 8);
            } else {
                bv0 = (s16x8){0,0,0,0,0,0,0,0}; bv1 = (s16x8){0,0,0,0,0,0,0,0};
            }
        } else {
            bf16x8 v0, v1;
            if (bn < N) {
                const float* bp2 = (const float*)Bp + (size_t)bn * K + k0 + hf * 16;
                float4 b0 = *reinterpret_cast<const float4*>(bp2);
                float4 b1 = *reinterpret_cast<const float4*>(bp2 + 4);
                float4 b2 = *reinterpret_cast<const float4*>(bp2 + 8);
                float4 b3 = *reinterpret_cast<const float4*>(bp2 + 12);
                v0[0]=(__bf16)b0.x; v0[1]=(__bf16)b0.y; v0[2]=(__bf16)b0.z; v0[3]=(__bf16)b0.w;
                v0[4]=(__bf16)b1.x; v0[5]=(__bf16)b1.y; v0[6]=(__bf16)b1.z; v0[7]=(__bf16)b1.w;
                v1[0]=(__bf16)b2.x; v1[1]=(__bf16)b2.y; v1[2]=(__bf16)b2.z; v1[3]=(__bf16)b2.w;
                v1[4]=(__bf16)b3.x; v1[5]=(__bf16)b3.y; v1[6]=(__bf16)b3.z; v1[7]=(__bf16)b3.w;
            } else {
                #pragma unroll
                for (int q = 0; q < 8; q++) { v0[q] = (__bf16)0.f; v1[q] = (__bf16)0.f; }
            }
            bv0 = __builtin_bit_cast(s16x8, v0); bv1 = __builtin_bit_cast(s16x8, v1);
        }
        __syncthreads();   // previous iter's LDS reads done
        *reinterpret_cast<s16x8*>(&As[r * LDT + hf * 16])     = av0;
        *reinterpret_cast<s16x8*>(&As[r * LDT + hf * 16 + 8]) = av1;
        *reinterpret_cast<s16x8*>(&Bs[r * LDT + hf * 16])     = bv0;
        *reinterpret_cast<s16x8*>(&Bs[r * LDT + hf * 16 + 8]) = bv1;
        __syncthreads();

        s16x8 af[4], bf[4];
        #pragma unroll
        for (int i = 0; i < 4; i++)
            af[i] = *reinterpret_cast<const s16x8*>(&As[(wm * 64 + i * 16 + l15) * LDT + l4 * 8]);
        #pragma unroll
        for (int j = 0; j < 4; j++)
            bf[j] = *reinterpret_cast<const s16x8*>(&Bs[(wn * 64 + j * 16 + l15) * LDT + l4 * 8]);
        #pragma unroll
        for (int i = 0; i < 4; i++)
            #pragma unroll
            for (int j = 0; j < 4; j++)
                acc[i][j] = __builtin_amdgcn_mfma_f32_16x16x32_bf16(af[i], bf[j], acc[i][j], 0, 0, 0);
    }

    #pragma unroll
    for (int j = 0; j < 4; j++) {
        int col = n0 + wn * 64 + j * 16 + l15;
        if (col >= N) continue;
        float bv = bias[col];
        #pragma unroll
        for (int i = 0; i < 4; i++) {
            int row = m0 + wm * 64 + i * 16 + l4 * 4;
            #pragma unroll
            for (int q = 0; q < 4; q++) {
                float v = acc[i][j][q] + bv;
                if (EPI == 1) { v = fmaxf(v, 0.f); v = v * v; }
                if constexpr (OUT16)
                    ((__bf16*)Cp)[(size_t)(row + q) * N + col] = (__bf16)v;
                else
                    ((float*)Cp)[(size_t)(row + q) * N + col] = v;
            }
        }
    }
}

// GEMM wrappers
__global__ __launch_bounds__(256) void gemm_bt16_k(const __bf16* A, const __bf16* B,
                                                   const float* bias, float* C,
                                                   int N, int K) {
    __shared__ __bf16 lds[2 * 128 * 40];
    mfma_tile<true, true, 0, false>(A, B, bias, C, blockIdx.y * 128, blockIdx.x * 128,
                                    N, K, lds, lds + 128 * 40);
}
__global__ __launch_bounds__(256) void gemm_head16_k(const float* A, const float* B,
                                                     const float* bias, __bf16* C,
                                                     int N, int K) {
    __shared__ __bf16 lds[2 * 128 * 40];
    mfma_tile<false, false, 1, true>(A, B, bias, C, blockIdx.y * 128, blockIdx.x * 128,
                                     N, K, lds, lds + 128 * 40);
}
__global__ __launch_bounds__(256) void gemm_b16o16_k(const __bf16* A, const __bf16* B,
                                                     const float* bias, __bf16* C,
                                                     int N, int K) {
    __shared__ __bf16 lds[2 * 128 * 40];
    mfma_tile<true, true, 0, true>(A, B, bias, C, blockIdx.y * 128, blockIdx.x * 128,
                                   N, K, lds, lds + 128 * 40);
}
__global__ __launch_bounds__(256) void gemm_bf16_logits(const float* A, const float* B,
                                                        const float* bias, float* C,
                                                        int N, int K) {
    __shared__ __bf16 lds[2 * 128 * 40];
    mfma_tile<false, false, 0, false>(A, B, bias, C, blockIdx.y * 128, blockIdx.x * 128,
                                      N, K, lds, lds + 128 * 40);
}

// ---------------------------------------------------------------------------
// GRU gates
// ---------------------------------------------------------------------------
__device__ __forceinline__ float fast_sigmoid(float x) {
    x = fminf(fmaxf(x, -30.f), 30.f);
    return __builtin_amdgcn_rcpf(1.f + __expf(-x));
}
__device__ __forceinline__ float fast_tanh(float x) {
    x = fminf(fmaxf(x, -15.f), 15.f);
    float e = __expf(2.f * x);
    return (e - 1.f) * __builtin_amdgcn_rcpf(e + 1.f);
}

// ---------------------------------------------------------------------------
// GRU v8: XCD-clustered + ACQUIRE-FENCE poll.
// Mechanism (r7/r8/r9 evidence): CDNA vector L1 is write-through => the
// producer's plain store lands in the SHARED XCD-L2 (r8: FETCH 61->19MB shows
// on-XCD service). The reader's plain load is served from its own stale L1
// (r7: spin-until-rescue). Fix: agent-scope acquire fence each retry
// (__builtin_amdgcn_fence -> buffer_inv: invalidates reader L1; dirty/local
// L2 lines survive) then a PLAIN load -> L2-hit sees the new data. Rescue:
// if still canary, an sc0 sc1 MALL load of the mirror in the same retry =>
// worst case ~ v4 latency + fence overhead, no hang.
// ---------------------------------------------------------------------------
__global__ __launch_bounds__(384, 1) void gru_x_kernel(const float* __restrict__ GX,
                                                       const float* __restrict__ Whh,
                                                       const float* __restrict__ bhh,
                                                       float* __restrict__ states,
                                                       float* __restrict__ states_m,
                                                       unsigned* __restrict__ cflags) {
    extern __shared__ float h_s[];
    __shared__ int sh_role;
    const int tid = threadIdx.x;

    unsigned xcc = 0;
    asm volatile("s_getreg_b32 %0, hwreg(HW_REG_XCC_ID)" : "=s"(xcc));
    xcc &= 0xff;
    if (blockIdx.x == 0 && tid == 0)
        __hip_atomic_store(&cflags[0], xcc + 1u, __ATOMIC_RELEASE, __HIP_MEMORY_SCOPE_AGENT);
    if (tid == 0) {
        unsigned tv;
        do { tv = __hip_atomic_load(&cflags[0], __ATOMIC_ACQUIRE, __HIP_MEMORY_SCOPE_AGENT); } while (tv == 0u);
        int role = -1;
        if (xcc == tv - 1u)
            role = (int)__hip_atomic_fetch_add(&cflags[1], 1u, __ATOMIC_RELAXED, __HIP_MEMORY_SCOPE_AGENT);
        sh_role = role;
    }
    __syncthreads();
    const int role = sh_role;
    if (role < 0 || role >= NROLE) return;

    const int tx   = tid & 15;         // k-slice (48 floats)
    const int ty   = tid >> 4;         // 0..23: unit within role
    const int gu   = role * 24 + ty;
    const int wave = tid >> 6;         // 0..5
    const int lane = tid & 63;

    // W_hh rows into registers: 3 gates x 48 floats
    float4 W4[3][12];
    #pragma unroll
    for (int p = 0; p < 3; p++) {
        const float* wr = &Whh[(size_t)(p * HID + gu) * HID + 4 * tx];
        #pragma unroll
        for (int j = 0; j < 12; j++)
            W4[p][j] = *reinterpret_cast<const float4*>(&wr[64 * j]);
    }
    float bh[3];
    #pragma unroll
    for (int p = 0; p < 3; p++) bh[p] = bhh[p * HID + gu];

    float hv  = 0.f;
    float gx0 = GX[0 * HID + gu];
    float gx1 = GX[1 * HID + gu];
    float gx2 = GX[2 * HID + gu];

    for (int t = 0; t < SEQ; t++) {
        float4 h4[12];
        if (t > 0) {
            if (tid < 192) {
                const float* pp = states   + (size_t)(t - 1) * HID + tid * 4;
                const float* pm = states_m + (size_t)(t - 1) * HID + tid * 4;
                u32x4 q;
                float s;
                for (;;) {
                    // invalidate reader L1 so the plain load sees the shared L2
                    __builtin_amdgcn_fence(__ATOMIC_ACQUIRE, "agent");
                    asm volatile(
                        "global_load_dwordx4 %0, %1, off\n\t"
                        "s_waitcnt vmcnt(0)"
                        : "=&v"(q) : "v"(pp) : "memory");
                    f32x4 f = __builtin_bit_cast(f32x4, q);
                    s = f[0] + f[1] + f[2] + f[3];
                    if (s == s) break;
                    // rescue: MALL-coherent load of the mirror
                    asm volatile(
                        "global_load_dwordx4 %0, %1, off sc0 sc1\n\t"
                        "s_waitcnt vmcnt(0)"
                        : "=&v"(q) : "v"(pm) : "memory");
                    f = __builtin_bit_cast(f32x4, q);
                    s = f[0] + f[1] + f[2] + f[3];
                    if (s == s) break;
                }
                *reinterpret_cast<u32x4*>(&h_s[tid * 4]) = q;
            }
            __syncthreads();
            #pragma unroll
            for (int j = 0; j < 12; j++)
                h4[j] = *reinterpret_cast<const float4*>(&h_s[4 * tx + 64 * j]);
        } else {
            #pragma unroll
            for (int j = 0; j < 12; j++) h4[j] = make_float4(0.f, 0.f, 0.f, 0.f);
        }

        // prefetch next step's gx AFTER the poll (off the poll's waitcnt path;
        // lands during compute+publish, consumed next step)
        float ngx0 = 0.f, ngx1 = 0.f, ngx2 = 0.f;
        if (t + 1 < SEQ) {
            const float* gp = &GX[(size_t)(t + 1) * G3];
            ngx0 = gp[0 * HID + gu];
            ngx1 = gp[1 * HID + gu];
            ngx2 = gp[2 * HID + gu];
        }

        float accp[3];
        #pragma unroll
        for (int p = 0; p < 3; p++) {
            float a = 0.f;
            #pragma unroll
            for (int j = 0; j < 12; j++) {
                a = fmaf(W4[p][j].x, h4[j].x, a);
                a = fmaf(W4[p][j].y, h4[j].y, a);
                a = fmaf(W4[p][j].z, h4[j].z, a);
                a = fmaf(W4[p][j].w, h4[j].w, a);
            }
            accp[p] = a;
        }
        #pragma unroll
        for (int p = 0; p < 3; p++) {
            accp[p] += __shfl_xor(accp[p], 1);
            accp[p] += __shfl_xor(accp[p], 2);
            accp[p] += __shfl_xor(accp[p], 4);
            accp[p] += __shfl_xor(accp[p], 8);
        }

        float r = fast_sigmoid(gx0 + accp[0] + bh[0]);
        float z = fast_sigmoid(gx1 + accp[1] + bh[1]);
        float n = fast_tanh(gx2 + r * (accp[2] + bh[2]));
        hv = (1.f - z) * n + z * hv;

        // dual publish: plain store -> write-through L1 into SHARED XCD-L2;
        // mirror sc0 sc1 -> MALL (rescue path).
        float v0 = __shfl(hv, 0);
        float v1 = __shfl(hv, 16);
        float v2 = __shfl(hv, 32);
        float v3 = __shfl(hv, 48);
        if (lane == 0) {
            f32x4 pv = {v0, v1, v2, v3};
            size_t o = (size_t)t * HID + role * 24 + wave * 4;
            float* dp = states + o;
            float* dm = states_m + o;
            asm volatile(
                "global_store_dwordx4 %0, %2, off\n\t"
                "global_store_dwordx4 %1, %2, off sc0 sc1"
                :: "v"(dp), "v"(dm), "v"(pv) : "memory");
        }
        gx0 = ngx0; gx1 = ngx1; gx2 = ngx2;
    }
}

// ---------------------------------------------------------------------------
// GRU v4 (fallback path; 48 WGs, sc0+sc1 rendezvous — r4/r5 verified)
// ---------------------------------------------------------------------------
__global__ __launch_bounds__(256, 1) void gru_kernel(const float* __restrict__ GX,
                                                     const float* __restrict__ Whh,
                                                     const float* __restrict__ bhh,
                                                     float* __restrict__ states) {
    __shared__ float h_s[HID];
    const int tid  = threadIdx.x;
    const int g    = blockIdx.x;
    const int tx   = tid & 15;
    const int ty   = tid >> 4;
    const int gu   = g * 16 + ty;
    const int wave = tid >> 6;
    const int lane = tid & 63;

    float4 W4[3][12];
    #pragma unroll
    for (int p = 0; p < 3; p++) {
        const float* wr = &Whh[(size_t)(p * HID + gu) * HID + 4 * tx];
        #pragma unroll
        for (int j = 0; j < 12; j++)
            W4[p][j] = *reinterpret_cast<const float4*>(&wr[64 * j]);
    }
    float bh[3];
    #pragma unroll
    for (int p = 0; p < 3; p++) bh[p] = bhh[p * HID + gu];

    float hv  = 0.f;
    float gx0 = GX[0 * HID + gu];
    float gx1 = GX[1 * HID + gu];
    float gx2 = GX[2 * HID + gu];

    for (int t = 0; t < SEQ; t++) {
        float ngx0 = 0.f, ngx1 = 0.f, ngx2 = 0.f;
        if (t + 1 < SEQ) {
            const float* gp = &GX[(size_t)(t + 1) * G3];
            ngx0 = gp[0 * HID + gu];
            ngx1 = gp[1 * HID + gu];
            ngx2 = gp[2 * HID + gu];
        }

        float4 h4[12];
        if (t > 0) {
            if (tid < 192) {
                const float* pp = states + (size_t)(t - 1) * HID + tid * 4;
                u32x4 q;
                float s;
                do {
                    asm volatile(
                        "global_load_dwordx4 %0, %1, off sc0 sc1\n\t"
                        "s_waitcnt vmcnt(0)"
                        : "=&v"(q) : "v"(pp) : "memory");
                    f32x4 f = __builtin_bit_cast(f32x4, q);
                    s = f[0] + f[1] + f[2] + f[3];
                } while (s != s);
                *reinterpret_cast<u32x4*>(&h_s[tid * 4]) = q;
            }
            __syncthreads();
            #pragma unroll
            for (int j = 0; j < 12; j++)
                h4[j] = *reinterpret_cast<const float4*>(&h_s[4 * tx + 64 * j]);
        } else {
            #pragma unroll
            for (int j = 0; j < 12; j++) h4[j] = make_float4(0.f, 0.f, 0.f, 0.f);
        }

        float accp[3];
        #pragma unroll
        for (int p = 0; p < 3; p++) {
            float a = 0.f;
            #pragma unroll
            for (int j = 0; j < 12; j++) {
                a = fmaf(W4[p][j].x, h4[j].x, a);
                a = fmaf(W4[p][j].y, h4[j].y, a);
                a = fmaf(W4[p][j].z, h4[j].z, a);
                a = fmaf(W4[p][j].w, h4[j].w, a);
            }
            accp[p] = a;
        }
        #pragma unroll
        for (int p = 0; p < 3; p++) {
            accp[p] += __shfl_xor(accp[p], 1);
            accp[p] += __shfl_xor(accp[p], 2);
            accp[p] += __shfl_xor(accp[p], 4);
            accp[p] += __shfl_xor(accp[p], 8);
        }

        float r = fast_sigmoid(gx0 + accp[0] + bh[0]);
        float z = fast_sigmoid(gx1 + accp[1] + bh[1]);
        float n = fast_tanh(gx2 + r * (accp[2] + bh[2]));
        hv = (1.f - z) * n + z * hv;

        float v0 = __shfl(hv, 0);
        float v1 = __shfl(hv, 16);
        float v2 = __shfl(hv, 32);
        float v3 = __shfl(hv, 48);
        if (lane == 0) {
            f32x4 pv = {v0, v1, v2, v3};
            float* dp = states + (size_t)t * HID + g * 16 + wave * 4;
            asm volatile(
                "global_store_dwordx4 %0, %1, off sc0 sc1"
                :: "v"(dp), "v"(pv) : "memory");
        }
        gx0 = ngx0; gx1 = ngx1; gx2 = ngx2;
    }
}

// ---------------------------------------------------------------------------
// chunk means / attention / scatter (unchanged, verified)
// ---------------------------------------------------------------------------
__global__ __launch_bounds__(256) void chunkmean_kernel(const float* __restrict__ states,
                                                        float* __restrict__ chunked) {
    int c = blockIdx.x;
    for (int e = threadIdx.x; e < HID; e += 256) {
        float s = 0.f;
        #pragma unroll 8
        for (int i = 0; i < CSZ; i++)
            s += states[(size_t)(c * CSZ + i) * HID + e];
        chunked[c * HID + e] = s * (1.f / 64.f);
    }
}

__global__ void attn_kernel(const float* __restrict__ qk,
                            const float* __restrict__ mk,
                            float* __restrict__ attn) {
    int s = blockIdx.x;
    int lane = threadIdx.x;
    int c = lane & 31;
    int h = lane >> 5;
    const float* q = &qk[(size_t)s * MDIM];
    const float* m = &mk[(size_t)c * MDIM];
    float sc = 0.f;
    for (int k = h; k < MDIM; k += 2) sc = fmaf(q[k], m[k], sc);
    sc += __shfl_xor(sc, 32);
    sc *= (1.0f / 16.0f);
    bool allowed = (CSZ * c + (CSZ - 1)) < s;
    float v = allowed ? sc : -3.4e38f;
    float mx = v;
    #pragma unroll
    for (int d = 16; d >= 1; d >>= 1) mx = fmaxf(mx, __shfl_xor(mx, d));
    float e = (allowed && mx > -1e37f) ? expf(sc - mx) : 0.f;
    float sm = e;
    #pragma unroll
    for (int d = 16; d >= 1; d >>= 1) sm += __shfl_xor(sm, d);
    float a = (sm > 0.f) ? e / sm : 0.f;
    if (lane < 32) attn[(size_t)s * NCHUNK + c] = a;
}

__global__ __launch_bounds__(256) void total_scatter_kernel(const float* __restrict__ bp,
                                                            const float* __restrict__ cp,
                                                            const float* __restrict__ attn,
                                                            const int* __restrict__ uids,
                                                            float* __restrict__ out) {
    int s = blockIdx.x;
    __shared__ float a_s[NCHUNK];
    if (threadIdx.x < NCHUNK) a_s[threadIdx.x] = attn[(size_t)s * NCHUNK + threadIdx.x];
    __syncthreads();
    for (int u = threadIdx.x; u < UDIM; u += 256) {
        float t = bp[(size_t)s * UDIM + u];
        #pragma unroll 8
        for (int c = 0; c < NCHUNK; c++)
            t = fmaf(a_s[c], cp[(size_t)c * UDIM + u], t);
        atomicAdd(&out[(size_t)s * VOC + uids[u]], t);
    }
}

// ---------------------------------------------------------------------------
// launch
// ---------------------------------------------------------------------------
static inline int cvt_grid(int n8) {
    int g = (n8 + 255) / 256;
    return g > 2048 ? 2048 : g;
}

extern "C" void kernel_launch(void* const* d_in, const int* in_sizes, int n_in,
                              void* d_out, int out_size, void* d_ws, size_t ws_size,
                              hipStream_t stream) {
    const int*   ids   = (const int*)d_in[0];
    const int*   uids  = (const int*)d_in[1];
    const float* emb   = (const float*)d_in[2];
    const float* w_ih  = (const float*)d_in[3];
    const float* w_hh  = (const float*)d_in[4];
    const float* b_ih  = (const float*)d_in[5];
    const float* b_hh  = (const float*)d_in[6];
    const float* Wq    = (const float*)d_in[7];
    const float* bq    = (const float*)d_in[8];
    const float* Wk    = (const float*)d_in[9];
    const float* bk    = (const float*)d_in[10];
    const float* Whf   = (const float*)d_in[11];
    const float* bhf   = (const float*)d_in[12];
    const float* Whp   = (const float*)d_in[13];
    const float* bhp   = (const float*)d_in[14];
    const float* Wcv   = (const float*)d_in[15];
    const float* bcv   = (const float*)d_in[16];
    const float* Wph   = (const float*)d_in[17];
    const float* bph   = (const float*)d_in[18];
    const float* obias = (const float*)d_in[19];
    float* out = (float*)d_out;
    float* wsf = (float*)d_ws;

    // common workspace (floats)
    size_t off = 0;
    float* GX     = wsf + off; off += (size_t)SEQ * G3;
    float* states = wsf + off; off += (size_t)SEQ * HID;
    float* head   = wsf + off; off += (size_t)SEQ * E4;     // fallback only
    float* bfeat  = wsf + off; off += (size_t)SEQ * EMB;    // fallback only
    float* chunk  = wsf + off; off += (size_t)NCHUNK * HID;
    float* qk     = wsf + off; off += (size_t)SEQ * MDIM;
    float* mk     = wsf + off; off += (size_t)NCHUNK * MDIM;
    float* cv     = wsf + off; off += (size_t)NCHUNK * EMB;
    float* cp     = wsf + off; off += (size_t)NCHUNK * UDIM;
    float* bp     = wsf + off; off += (size_t)SEQ * UDIM;
    float* attn   = wsf + off; off += (size_t)SEQ * NCHUNK;
    size_t common_off = off;

    // big-path extras (bf16 counted as /2 floats)
    __bf16* X16     = (__bf16*)(wsf + off); off += (size_t)SEQ * EMB / 2;
    __bf16* emb16   = (__bf16*)(wsf + off); off += (size_t)VOC * EMB / 2;
    __bf16* wih16   = (__bf16*)(wsf + off); off += (size_t)G3 * EMB / 2;
    __bf16* Whp16   = (__bf16*)(wsf + off); off += (size_t)EMB * E4 / 2;
    __bf16* Wph16   = (__bf16*)(wsf + off); off += (size_t)UDIM * EMB / 2;
    __bf16* head16  = (__bf16*)(wsf + off); off += (size_t)SEQ * E4 / 2;
    __bf16* bfeat16 = (__bf16*)(wsf + off); off += (size_t)SEQ * EMB / 2;
    float* states_m = wsf + off; off += (size_t)SEQ * HID;   // mirror (MALL path)
    unsigned* flags = (unsigned*)(wsf + off); off += 64;
    const bool big = ws_size >= off * sizeof(float);

    if (big) {
        // pre-GRU critical path kept minimal: only wih16 cvt + gather + GX
        cvt_f32_bf16<<<cvt_grid(G3 * EMB / 8), 256, 0, stream>>>(w_ih, wih16, G3 * EMB / 8);
        embed16c_kernel<<<SEQ, 64, 0, stream>>>(ids, emb, X16);
        hipMemsetAsync(states,   0xFF, (size_t)SEQ * HID * sizeof(float), stream);
        hipMemsetAsync(states_m, 0xFF, (size_t)SEQ * HID * sizeof(float), stream);
        hipMemsetAsync(flags, 0, 64 * sizeof(unsigned), stream);
        gemm_bt16_k<<<dim3(G3 / 128, SEQ / 128), 256, 0, stream>>>(X16, wih16, b_ih, GX, G3, EMB);
        // XCD-clustered GRU with acquire-fence poll
        (void)hipFuncSetAttribute((const void*)gru_x_kernel,
                                  hipFuncAttributeMaxDynamicSharedMemorySize, 98304);
        gru_x_kernel<<<256, 384, 98304, stream>>>(GX, w_hh, b_hh, states, states_m, flags);
        // post-GRU: remaining weight conversions + chain
        cvt_f32_bf16<<<cvt_grid(VOC * EMB / 8), 256, 0, stream>>>(emb, emb16, VOC * EMB / 8);
        cvt_f32_bf16<<<cvt_grid(EMB * E4 / 8), 256, 0, stream>>>(Whp, Whp16, EMB * E4 / 8);
        cvt_f32_bf16<<<cvt_grid(UDIM * EMB / 8), 256, 0, stream>>>(Wph, Wph16, UDIM * EMB / 8);
        chunkmean_kernel<<<NCHUNK, 256, 0, stream>>>(states, chunk);
        gemm_nt<0><<<dim3(MDIM / 128, SEQ / 128), 256, 0, stream>>>(states, Wq, bq, qk, SEQ, MDIM, HID);
        gemm_nt<0><<<dim3(MDIM / 128, 1), 256, 0, stream>>>(chunk, Wk, bk, mk, NCHUNK, MDIM, HID);
        gemm_head16_k<<<dim3(E4 / 128, SEQ / 128), 256, 0, stream>>>(states, Whf, bhf, head16, E4, HID);
        gemm_b16o16_k<<<dim3(EMB / 128, SEQ / 128), 256, 0, stream>>>(head16, Whp16, bhp, bfeat16, EMB, E4);
        gemm_nt<0><<<dim3(EMB / 128, 1), 256, 0, stream>>>(chunk, Wcv, bcv, cv, NCHUNK, EMB, HID);
        gemm_nt<0><<<dim3(UDIM / 128, 1), 256, 0, stream>>>(cv, Wph, bph, cp, NCHUNK, UDIM, EMB);
        gemm_bt16_k<<<dim3(UDIM / 128, SEQ / 128), 256, 0, stream>>>(bfeat16, Wph16, bph, bp, UDIM, EMB);
        gemm_bt16_k<<<dim3((VOC + 127) / 128, SEQ / 128), 256, 0, stream>>>(bfeat16, emb16, obias, out, VOC, EMB);
        attn_kernel<<<SEQ, 64, 0, stream>>>(qk, mk, attn);
        total_scatter_kernel<<<SEQ, 256, 0, stream>>>(bp, cp, attn, uids, out);
    } else {
        // fallback: round-4/5 serial path
        float* X = wsf + common_off;
        embed_kernel<<<SEQ, 256, 0, stream>>>(ids, emb, X);
        hipMemsetAsync(states, 0xFF, (size_t)SEQ * HID * sizeof(float), stream);
        gemm_nt<0><<<dim3(G3 / 128, SEQ / 128), 256, 0, stream>>>(X, w_ih, b_ih, GX, SEQ, G3, EMB);
        gru_kernel<<<G_GRU, 256, 0, stream>>>(GX, w_hh, b_hh, states);
        chunkmean_kernel<<<NCHUNK, 256, 0, stream>>>(states, chunk);
        gemm_nt<0><<<dim3(MDIM / 128, SEQ / 128), 256, 0, stream>>>(states, Wq, bq, qk, SEQ, MDIM, HID);
        gemm_nt<0><<<dim3(MDIM / 128, 1), 256, 0, stream>>>(chunk, Wk, bk, mk, NCHUNK, MDIM, HID);
        gemm_nt<1><<<dim3(E4 / 128, SEQ / 128), 256, 0, stream>>>(states, Whf, bhf, head, SEQ, E4, HID);
        gemm_nt<0><<<dim3(EMB / 128, SEQ / 128), 256, 0, stream>>>(head, Whp, bhp, bfeat, SEQ, EMB, E4);
        gemm_nt<0><<<dim3(EMB / 128, 1), 256, 0, stream>>>(chunk, Wcv, bcv, cv, NCHUNK, EMB, HID);
        gemm_nt<0><<<dim3(UDIM / 128, 1), 256, 0, stream>>>(cv, Wph, bph, cp, NCHUNK, UDIM, EMB);
        gemm_nt<0><<<dim3(UDIM / 128, SEQ / 128), 256, 0, stream>>>(bfeat, Wph, bph, bp, SEQ, UDIM, EMB);
        gemm_bf16_logits<<<dim3((VOC + 127) / 128, SEQ / 128), 256, 0, stream>>>(bfeat, emb, obias, out, VOC, EMB);
        attn_kernel<<<SEQ, 64, 0, stream>>>(qk, mk, attn);
        total_scatter_kernel<<<SEQ, 256, 0, stream>>>(bp, cp, attn, uids, out);
    }
}

// Round 11
// 5045.989 us; speedup vs baseline: 2.9002x; 2.9002x over previous
//
#include <hip/hip_runtime.h>
#include <hip/hip_bf16.h>
#include <math.h>

// Problem constants
#define SEQ   2048
#define VOC   50257
#define EMB   512
#define HID   768
#define G3    2304      // 3*HID
#define MDIM  256
#define CSZ   64
#define NCHUNK 32
#define UDIM  2048
#define E4    2048      // 4*EMB

#define G_GRU 48
#define CANARY 0xFFFFFFFFu   // -NaN; GRU h is always finite => unreachable

typedef uint32_t u32x4  __attribute__((ext_vector_type(4)));
typedef float    f32x4  __attribute__((ext_vector_type(4)));
typedef short    s16x8  __attribute__((ext_vector_type(8)));   // 8 bf16 (4 VGPRs)
typedef __bf16   bf16x8 __attribute__((ext_vector_type(8)));

// ---------------------------------------------------------------------------
// fp32 -> bf16 convert (grid-stride, 8 elems/thread)
// ---------------------------------------------------------------------------
__global__ __launch_bounds__(256) void cvt_f32_bf16(const float* __restrict__ src,
                                                    __bf16* __restrict__ dst, int n8) {
    int stride = gridDim.x * 256;
    for (int i = blockIdx.x * 256 + threadIdx.x; i < n8; i += stride) {
        const float4* s = reinterpret_cast<const float4*>(src + (size_t)i * 8);
        float4 a = s[0], b = s[1];
        bf16x8 o;
        o[0]=(__bf16)a.x; o[1]=(__bf16)a.y; o[2]=(__bf16)a.z; o[3]=(__bf16)a.w;
        o[4]=(__bf16)b.x; o[5]=(__bf16)b.y; o[6]=(__bf16)b.z; o[7]=(__bf16)b.w;
        *reinterpret_cast<bf16x8*>(dst + (size_t)i * 8) = o;
    }
}

// ---------------------------------------------------------------------------
// Embedding gathers
// ---------------------------------------------------------------------------
__global__ __launch_bounds__(256) void embed_kernel(const int* __restrict__ ids,
                                                    const float* __restrict__ emb,
                                                    float* __restrict__ X) {
    int s = blockIdx.x;
    int id = ids[s];
    const float* src = &emb[(size_t)id * EMB];
    float* dst = &X[(size_t)s * EMB];
    for (int i = threadIdx.x; i < EMB; i += 256) dst[i] = src[i];
}

// gather + convert from fp32 emb directly (keeps emb16 cvt off pre-GRU path)
__global__ __launch_bounds__(64) void embed16c_kernel(const int* __restrict__ ids,
                                                      const float* __restrict__ emb,
                                                      __bf16* __restrict__ X16) {
    int s = blockIdx.x;
    int id = ids[s];
    const float4* src = reinterpret_cast<const float4*>(emb + (size_t)id * EMB);
    int i = threadIdx.x;              // 64 threads x 8 floats = 512
    float4 a = src[i * 2], b = src[i * 2 + 1];
    bf16x8 o;
    o[0]=(__bf16)a.x; o[1]=(__bf16)a.y; o[2]=(__bf16)a.z; o[3]=(__bf16)a.w;
    o[4]=(__bf16)b.x; o[5]=(__bf16)b.y; o[6]=(__bf16)b.z; o[7]=(__bf16)b.w;
    reinterpret_cast<bf16x8*>(X16 + (size_t)s * EMB)[i] = o;
}

// ---------------------------------------------------------------------------
// Generic fp32 GEMM (128x128, BK=16). EPI 1 = relu^2.
// ---------------------------------------------------------------------------
template<int EPI>
__global__ __launch_bounds__(256) void gemm_nt(const float* __restrict__ A,
                                               const float* __restrict__ B,
                                               const float* __restrict__ bias,
                                               float* __restrict__ C,
                                               int M, int N, int K) {
    __shared__ float As[16][132];
    __shared__ float Bs[16][132];
    const int tid = threadIdx.x;
    const int tx = tid & 15;
    const int ty = tid >> 4;
    const int m0 = blockIdx.y * 128;
    const int n0 = blockIdx.x * 128;

    float acc[8][8];
    #pragma unroll
    for (int i = 0; i < 8; i++)
        #pragma unroll
        for (int j = 0; j < 8; j++) acc[i][j] = 0.f;

    for (int k0 = 0; k0 < K; k0 += 16) {
        #pragma unroll
        for (int i = 0; i < 2; i++) {
            int idx = tid * 2 + i;
            int r   = idx >> 2;
            int c4  = idx & 3;
            float4 av = {0.f, 0.f, 0.f, 0.f};
            float4 bv = {0.f, 0.f, 0.f, 0.f};
            int ar = m0 + r;
            if (ar < M) av = *reinterpret_cast<const float4*>(&A[(size_t)ar * K + k0 + c4 * 4]);
            int br = n0 + r;
            if (br < N) bv = *reinterpret_cast<const float4*>(&B[(size_t)br * K + k0 + c4 * 4]);
            As[c4 * 4 + 0][r] = av.x; As[c4 * 4 + 1][r] = av.y;
            As[c4 * 4 + 2][r] = av.z; As[c4 * 4 + 3][r] = av.w;
            Bs[c4 * 4 + 0][r] = bv.x; Bs[c4 * 4 + 1][r] = bv.y;
            Bs[c4 * 4 + 2][r] = bv.z; Bs[c4 * 4 + 3][r] = bv.w;
        }
        __syncthreads();
        #pragma unroll
        for (int k = 0; k < 16; k++) {
            float4 a0 = *reinterpret_cast<const float4*>(&As[k][ty * 4]);
            float4 a1 = *reinterpret_cast<const float4*>(&As[k][64 + ty * 4]);
            float4 b0 = *reinterpret_cast<const float4*>(&Bs[k][tx * 4]);
            float4 b1 = *reinterpret_cast<const float4*>(&Bs[k][64 + tx * 4]);
            float a[8] = {a0.x, a0.y, a0.z, a0.w, a1.x, a1.y, a1.z, a1.w};
            float b[8] = {b0.x, b0.y, b0.z, b0.w, b1.x, b1.y, b1.z, b1.w};
            #pragma unroll
            for (int i = 0; i < 8; i++)
                #pragma unroll
                for (int j = 0; j < 8; j++)
                    acc[i][j] = fmaf(a[i], b[j], acc[i][j]);
        }
        __syncthreads();
    }

    #pragma unroll
    for (int i = 0; i < 8; i++) {
        int r = m0 + ((i < 4) ? (ty * 4 + i) : (64 + ty * 4 + (i - 4)));
        if (r >= M) continue;
        #pragma unroll
        for (int j = 0; j < 8; j++) {
            int c = n0 + ((j < 4) ? (tx * 4 + j) : (64 + tx * 4 + (j - 4)));
            if (c >= N) continue;
            float v = acc[i][j] + bias[c];
            if (EPI == 1) { v = fmaxf(v, 0.f); v = v * v; }
            C[(size_t)r * N + c] = v;
        }
    }
}

// ---------------------------------------------------------------------------
// Device MFMA tile: C[128 x 128] at (m0,n0) = A @ B^T + bias.
// (all four template variants numerically verified in rounds 3-10)
// ---------------------------------------------------------------------------
template<bool A16, bool B16, int EPI, bool OUT16>
__device__ void mfma_tile(const void* Ap, const void* Bp,
                          const float* __restrict__ bias, void* Cp,
                          int m0, int n0, int N, int K,
                          __bf16* As, __bf16* Bs) {
    constexpr int LDT = 40;
    const int tid  = threadIdx.x;
    const int lane = tid & 63;
    const int wave = tid >> 6;
    const int wm = wave >> 1, wn = wave & 1;
    const int l15 = lane & 15, l4 = lane >> 4;
    const int r = tid >> 1, hf = tid & 1;

    f32x4 acc[4][4];
    #pragma unroll
    for (int i = 0; i < 4; i++)
        #pragma unroll
        for (int j = 0; j < 4; j++) acc[i][j] = (f32x4){0.f, 0.f, 0.f, 0.f};

    for (int k0 = 0; k0 < K; k0 += 32) {
        s16x8 av0, av1, bv0, bv1;
        if constexpr (A16) {
            const __bf16* ap = (const __bf16*)Ap + (size_t)(m0 + r) * K + k0 + hf * 16;
            av0 = *reinterpret_cast<const s16x8*>(ap);
            av1 = *reinterpret_cast<const s16x8*>(ap + 8);
        } else {
            const float* ap = (const float*)Ap + (size_t)(m0 + r) * K + k0 + hf * 16;
            float4 a0 = *reinterpret_cast<const float4*>(ap);
            float4 a1 = *reinterpret_cast<const float4*>(ap + 4);
            float4 a2 = *reinterpret_cast<const float4*>(ap + 8);
            float4 a3 = *reinterpret_cast<const float4*>(ap + 12);
            bf16x8 w0, w1;
            w0[0]=(__bf16)a0.x; w0[1]=(__bf16)a0.y; w0[2]=(__bf16)a0.z; w0[3]=(__bf16)a0.w;
            w0[4]=(__bf16)a1.x; w0[5]=(__bf16)a1.y; w0[6]=(__bf16)a1.z; w0[7]=(__bf16)a1.w;
            w1[0]=(__bf16)a2.x; w1[1]=(__bf16)a2.y; w1[2]=(__bf16)a2.z; w1[3]=(__bf16)a2.w;
            w1[4]=(__bf16)a3.x; w1[5]=(__bf16)a3.y; w1[6]=(__bf16)a3.z; w1[7]=(__bf16)a3.w;
            av0 = __builtin_bit_cast(s16x8, w0); av1 = __builtin_bit_cast(s16x8, w1);
        }
        int bn = n0 + r;
        if constexpr (B16) {
            if (bn < N) {
                const __bf16* bp2 = (const __bf16*)Bp + (size_t)bn * K + k0 + hf * 16;
                bv0 = *reinterpret_cast<const s16x8*>(bp2);
                bv1 = *reinterpret_cast<const s16x8*>(bp2 + 8);
            } else {
                bv0 = (s16x8){0,0,0,0,0,0,0,0}; bv1 = (s16x8){0,0,0,0,0,0,0,0};
            }
        } else {
            bf16x8 v0, v1;
            if (bn < N) {
                const float* bp2 = (const float*)Bp + (size_t)bn * K + k0 + hf * 16;
                float4 b0 = *reinterpret_cast<const float4*>(bp2);
                float4 b1 = *reinterpret_cast<const float4*>(bp2 + 4);
                float4 b2 = *reinterpret_cast<const float4*>(bp2 + 8);
                float4 b3 = *reinterpret_cast<const float4*>(bp2 + 12);
                v0[0]=(__bf16)b0.x; v0[1]=(__bf16)b0.y; v0[2]=(__bf16)b0.z; v0[3]=(__bf16)b0.w;
                v0[4]=(__bf16)b1.x; v0[5]=(__bf16)b1.y; v0[6]=(__bf16)b1.z; v0[7]=(__bf16)b1.w;
                v1[0]=(__bf16)b2.x; v1[1]=(__bf16)b2.y; v1[2]=(__bf16)b2.z; v1[3]=(__bf16)b2.w;
                v1[4]=(__bf16)b3.x; v1[5]=(__bf16)b3.y; v1[6]=(__bf16)b3.z; v1[7]=(__bf16)b3.w;
            } else {
                #pragma unroll
                for (int q = 0; q < 8; q++) { v0[q] = (__bf16)0.f; v1[q] = (__bf16)0.f; }
            }
            bv0 = __builtin_bit_cast(s16x8, v0); bv1 = __builtin_bit_cast(s16x8, v1);
        }
        __syncthreads();   // previous iter's LDS reads done
        *reinterpret_cast<s16x8*>(&As[r * LDT + hf * 16])     = av0;
        *reinterpret_cast<s16x8*>(&As[r * LDT + hf * 16 + 8]) = av1;
        *reinterpret_cast<s16x8*>(&Bs[r * LDT + hf * 16])     = bv0;
        *reinterpret_cast<s16x8*>(&Bs[r * LDT + hf * 16 + 8]) = bv1;
        __syncthreads();

        s16x8 af[4], bf[4];
        #pragma unroll
        for (int i = 0; i < 4; i++)
            af[i] = *reinterpret_cast<const s16x8*>(&As[(wm * 64 + i * 16 + l15) * LDT + l4 * 8]);
        #pragma unroll
        for (int j = 0; j < 4; j++)
            bf[j] = *reinterpret_cast<const s16x8*>(&Bs[(wn * 64 + j * 16 + l15) * LDT + l4 * 8]);
        #pragma unroll
        for (int i = 0; i < 4; i++)
            #pragma unroll
            for (int j = 0; j < 4; j++)
                acc[i][j] = __builtin_amdgcn_mfma_f32_16x16x32_bf16(af[i], bf[j], acc[i][j], 0, 0, 0);
    }

    #pragma unroll
    for (int j = 0; j < 4; j++) {
        int col = n0 + wn * 64 + j * 16 + l15;
        if (col >= N) continue;
        float bv = bias[col];
        #pragma unroll
        for (int i = 0; i < 4; i++) {
            int row = m0 + wm * 64 + i * 16 + l4 * 4;
            #pragma unroll
            for (int q = 0; q < 4; q++) {
                float v = acc[i][j][q] + bv;
                if (EPI == 1) { v = fmaxf(v, 0.f); v = v * v; }
                if constexpr (OUT16)
                    ((__bf16*)Cp)[(size_t)(row + q) * N + col] = (__bf16)v;
                else
                    ((float*)Cp)[(size_t)(row + q) * N + col] = v;
            }
        }
    }
}

// GEMM wrappers
__global__ __launch_bounds__(256) void gemm_bt16_k(const __bf16* A, const __bf16* B,
                                                   const float* bias, float* C,
                                                   int N, int K) {
    __shared__ __bf16 lds[2 * 128 * 40];
    mfma_tile<true, true, 0, false>(A, B, bias, C, blockIdx.y * 128, blockIdx.x * 128,
                                    N, K, lds, lds + 128 * 40);
}
__global__ __launch_bounds__(256) void gemm_head16_k(const float* A, const float* B,
                                                     const float* bias, __bf16* C,
                                                     int N, int K) {
    __shared__ __bf16 lds[2 * 128 * 40];
    mfma_tile<false, false, 1, true>(A, B, bias, C, blockIdx.y * 128, blockIdx.x * 128,
                                     N, K, lds, lds + 128 * 40);
}
__global__ __launch_bounds__(256) void gemm_b16o16_k(const __bf16* A, const __bf16* B,
                                                     const float* bias, __bf16* C,
                                                     int N, int K) {
    __shared__ __bf16 lds[2 * 128 * 40];
    mfma_tile<true, true, 0, true>(A, B, bias, C, blockIdx.y * 128, blockIdx.x * 128,
                                   N, K, lds, lds + 128 * 40);
}
__global__ __launch_bounds__(256) void gemm_bf16_logits(const float* A, const float* B,
                                                        const float* bias, float* C,
                                                        int N, int K) {
    __shared__ __bf16 lds[2 * 128 * 40];
    mfma_tile<false, false, 0, false>(A, B, bias, C, blockIdx.y * 128, blockIdx.x * 128,
                                      N, K, lds, lds + 128 * 40);
}

// ---------------------------------------------------------------------------
// GRU gates
// ---------------------------------------------------------------------------
__device__ __forceinline__ float fast_sigmoid(float x) {
    x = fminf(fmaxf(x, -30.f), 30.f);
    return __builtin_amdgcn_rcpf(1.f + __expf(-x));
}
__device__ __forceinline__ float fast_tanh(float x) {
    x = fminf(fmaxf(x, -15.f), 15.f);
    float e = __expf(2.f * x);
    return (e - 1.f) * __builtin_amdgcn_rcpf(e + 1.f);
}

// ---------------------------------------------------------------------------
// GRU v4 (FINAL): 48 WGs x 256 threads, W_hh in registers, MALL rendezvous.
// Structural note (r7-r10 falsifications): per-step cross-CU visibility on
// MI355X is only reliable through the MALL (sc0 sc1); cheaper paths all fail
// (reader-L1 staleness for sc0 loads; atomic-RMW write-amplifies; acquire
// fence costs more than it saves). ~1.88us/step = ~2 MALL RTs is the floor
// for this recurrence's dataflow.
// ---------------------------------------------------------------------------
__global__ __launch_bounds__(256, 1) void gru_kernel(const float* __restrict__ GX,
                                                     const float* __restrict__ Whh,
                                                     const float* __restrict__ bhh,
                                                     float* __restrict__ states) {
    __shared__ float h_s[HID];
    const int tid  = threadIdx.x;
    const int g    = blockIdx.x;
    const int tx   = tid & 15;
    const int ty   = tid >> 4;
    const int gu   = g * 16 + ty;
    const int wave = tid >> 6;
    const int lane = tid & 63;

    float4 W4[3][12];
    #pragma unroll
    for (int p = 0; p < 3; p++) {
        const float* wr = &Whh[(size_t)(p * HID + gu) * HID + 4 * tx];
        #pragma unroll
        for (int j = 0; j < 12; j++)
            W4[p][j] = *reinterpret_cast<const float4*>(&wr[64 * j]);
    }
    float bh[3];
    #pragma unroll
    for (int p = 0; p < 3; p++) bh[p] = bhh[p * HID + gu];

    float hv  = 0.f;
    float gx0 = GX[0 * HID + gu];
    float gx1 = GX[1 * HID + gu];
    float gx2 = GX[2 * HID + gu];

    for (int t = 0; t < SEQ; t++) {
        float ngx0 = 0.f, ngx1 = 0.f, ngx2 = 0.f;
        if (t + 1 < SEQ) {
            const float* gp = &GX[(size_t)(t + 1) * G3];
            ngx0 = gp[0 * HID + gu];
            ngx1 = gp[1 * HID + gu];
            ngx2 = gp[2 * HID + gu];
        }

        float4 h4[12];
        if (t > 0) {
            if (tid < 192) {
                const float* pp = states + (size_t)(t - 1) * HID + tid * 4;
                u32x4 q;
                float s;
                do {
                    asm volatile(
                        "global_load_dwordx4 %0, %1, off sc0 sc1\n\t"
                        "s_waitcnt vmcnt(0)"
                        : "=&v"(q) : "v"(pp) : "memory");
                    f32x4 f = __builtin_bit_cast(f32x4, q);
                    s = f[0] + f[1] + f[2] + f[3];
                } while (s != s);   // NaN iff any word still canary
                *reinterpret_cast<u32x4*>(&h_s[tid * 4]) = q;
            }
            __syncthreads();
            #pragma unroll
            for (int j = 0; j < 12; j++)
                h4[j] = *reinterpret_cast<const float4*>(&h_s[4 * tx + 64 * j]);
        } else {
            #pragma unroll
            for (int j = 0; j < 12; j++) h4[j] = make_float4(0.f, 0.f, 0.f, 0.f);
        }

        float accp[3];
        #pragma unroll
        for (int p = 0; p < 3; p++) {
            float a = 0.f;
            #pragma unroll
            for (int j = 0; j < 12; j++) {
                a = fmaf(W4[p][j].x, h4[j].x, a);
                a = fmaf(W4[p][j].y, h4[j].y, a);
                a = fmaf(W4[p][j].z, h4[j].z, a);
                a = fmaf(W4[p][j].w, h4[j].w, a);
            }
            accp[p] = a;
        }
        #pragma unroll
        for (int p = 0; p < 3; p++) {
            accp[p] += __shfl_xor(accp[p], 1);
            accp[p] += __shfl_xor(accp[p], 2);
            accp[p] += __shfl_xor(accp[p], 4);
            accp[p] += __shfl_xor(accp[p], 8);
        }

        float r = fast_sigmoid(gx0 + accp[0] + bh[0]);
        float z = fast_sigmoid(gx1 + accp[1] + bh[1]);
        float n = fast_tanh(gx2 + r * (accp[2] + bh[2]));
        hv = (1.f - z) * n + z * hv;

        float v0 = __shfl(hv, 0);
        float v1 = __shfl(hv, 16);
        float v2 = __shfl(hv, 32);
        float v3 = __shfl(hv, 48);
        if (lane == 0) {
            f32x4 pv = {v0, v1, v2, v3};
            float* dp = states + (size_t)t * HID + g * 16 + wave * 4;
            asm volatile(
                "global_store_dwordx4 %0, %1, off sc0 sc1"
                :: "v"(dp), "v"(pv) : "memory");
        }
        gx0 = ngx0; gx1 = ngx1; gx2 = ngx2;
    }
}

// ---------------------------------------------------------------------------
// chunk means / attention / scatter (unchanged, verified)
// ---------------------------------------------------------------------------
__global__ __launch_bounds__(256) void chunkmean_kernel(const float* __restrict__ states,
                                                        float* __restrict__ chunked) {
    int c = blockIdx.x;
    for (int e = threadIdx.x; e < HID; e += 256) {
        float s = 0.f;
        #pragma unroll 8
        for (int i = 0; i < CSZ; i++)
            s += states[(size_t)(c * CSZ + i) * HID + e];
        chunked[c * HID + e] = s * (1.f / 64.f);
    }
}

__global__ void attn_kernel(const float* __restrict__ qk,
                            const float* __restrict__ mk,
                            float* __restrict__ attn) {
    int s = blockIdx.x;
    int lane = threadIdx.x;
    int c = lane & 31;
    int h = lane >> 5;
    const float* q = &qk[(size_t)s * MDIM];
    const float* m = &mk[(size_t)c * MDIM];
    float sc = 0.f;
    for (int k = h; k < MDIM; k += 2) sc = fmaf(q[k], m[k], sc);
    sc += __shfl_xor(sc, 32);
    sc *= (1.0f / 16.0f);
    bool allowed = (CSZ * c + (CSZ - 1)) < s;
    float v = allowed ? sc : -3.4e38f;
    float mx = v;
    #pragma unroll
    for (int d = 16; d >= 1; d >>= 1) mx = fmaxf(mx, __shfl_xor(mx, d));
    float e = (allowed && mx > -1e37f) ? expf(sc - mx) : 0.f;
    float sm = e;
    #pragma unroll
    for (int d = 16; d >= 1; d >>= 1) sm += __shfl_xor(sm, d);
    float a = (sm > 0.f) ? e / sm : 0.f;
    if (lane < 32) attn[(size_t)s * NCHUNK + c] = a;
}

__global__ __launch_bounds__(256) void total_scatter_kernel(const float* __restrict__ bp,
                                                            const float* __restrict__ cp,
                                                            const float* __restrict__ attn,
                                                            const int* __restrict__ uids,
                                                            float* __restrict__ out) {
    int s = blockIdx.x;
    __shared__ float a_s[NCHUNK];
    if (threadIdx.x < NCHUNK) a_s[threadIdx.x] = attn[(size_t)s * NCHUNK + threadIdx.x];
    __syncthreads();
    for (int u = threadIdx.x; u < UDIM; u += 256) {
        float t = bp[(size_t)s * UDIM + u];
        #pragma unroll 8
        for (int c = 0; c < NCHUNK; c++)
            t = fmaf(a_s[c], cp[(size_t)c * UDIM + u], t);
        atomicAdd(&out[(size_t)s * VOC + uids[u]], t);
    }
}

// ---------------------------------------------------------------------------
// launch
// ---------------------------------------------------------------------------
static inline int cvt_grid(int n8) {
    int g = (n8 + 255) / 256;
    return g > 2048 ? 2048 : g;
}

extern "C" void kernel_launch(void* const* d_in, const int* in_sizes, int n_in,
                              void* d_out, int out_size, void* d_ws, size_t ws_size,
                              hipStream_t stream) {
    const int*   ids   = (const int*)d_in[0];
    const int*   uids  = (const int*)d_in[1];
    const float* emb   = (const float*)d_in[2];
    const float* w_ih  = (const float*)d_in[3];
    const float* w_hh  = (const float*)d_in[4];
    const float* b_ih  = (const float*)d_in[5];
    const float* b_hh  = (const float*)d_in[6];
    const float* Wq    = (const float*)d_in[7];
    const float* bq    = (const float*)d_in[8];
    const float* Wk    = (const float*)d_in[9];
    const float* bk    = (const float*)d_in[10];
    const float* Whf   = (const float*)d_in[11];
    const float* bhf   = (const float*)d_in[12];
    const float* Whp   = (const float*)d_in[13];
    const float* bhp   = (const float*)d_in[14];
    const float* Wcv   = (const float*)d_in[15];
    const float* bcv   = (const float*)d_in[16];
    const float* Wph   = (const float*)d_in[17];
    const float* bph   = (const float*)d_in[18];
    const float* obias = (const float*)d_in[19];
    float* out = (float*)d_out;
    float* wsf = (float*)d_ws;

    // common workspace (floats)
    size_t off = 0;
    float* GX     = wsf + off; off += (size_t)SEQ * G3;
    float* states = wsf + off; off += (size_t)SEQ * HID;
    float* head   = wsf + off; off += (size_t)SEQ * E4;     // fallback only
    float* bfeat  = wsf + off; off += (size_t)SEQ * EMB;    // fallback only
    float* chunk  = wsf + off; off += (size_t)NCHUNK * HID;
    float* qk     = wsf + off; off += (size_t)SEQ * MDIM;
    float* mk     = wsf + off; off += (size_t)NCHUNK * MDIM;
    float* cv     = wsf + off; off += (size_t)NCHUNK * EMB;
    float* cp     = wsf + off; off += (size_t)NCHUNK * UDIM;
    float* bp     = wsf + off; off += (size_t)SEQ * UDIM;
    float* attn   = wsf + off; off += (size_t)SEQ * NCHUNK;
    size_t common_off = off;

    // big-path extras (bf16 counted as /2 floats)
    __bf16* X16     = (__bf16*)(wsf + off); off += (size_t)SEQ * EMB / 2;
    __bf16* emb16   = (__bf16*)(wsf + off); off += (size_t)VOC * EMB / 2;
    __bf16* wih16   = (__bf16*)(wsf + off); off += (size_t)G3 * EMB / 2;
    __bf16* Whp16   = (__bf16*)(wsf + off); off += (size_t)EMB * E4 / 2;
    __bf16* Wph16   = (__bf16*)(wsf + off); off += (size_t)UDIM * EMB / 2;
    __bf16* head16  = (__bf16*)(wsf + off); off += (size_t)SEQ * E4 / 2;
    __bf16* bfeat16 = (__bf16*)(wsf + off); off += (size_t)SEQ * EMB / 2;
    const bool big = ws_size >= off * sizeof(float);

    if (big) {
        // pre-GRU critical path kept minimal: wih16 cvt + fused gather/cvt + GX
        cvt_f32_bf16<<<cvt_grid(G3 * EMB / 8), 256, 0, stream>>>(w_ih, wih16, G3 * EMB / 8);
        embed16c_kernel<<<SEQ, 64, 0, stream>>>(ids, emb, X16);
        hipMemsetAsync(states, 0xFF, (size_t)SEQ * HID * sizeof(float), stream);
        gemm_bt16_k<<<dim3(G3 / 128, SEQ / 128), 256, 0, stream>>>(X16, wih16, b_ih, GX, G3, EMB);
        // GRU (v4: 48 WGs, MALL rendezvous — proven 3.86 ms)
        gru_kernel<<<G_GRU, 256, 0, stream>>>(GX, w_hh, b_hh, states);
        // post-GRU: remaining weight conversions + bf16-MFMA chain
        cvt_f32_bf16<<<cvt_grid(VOC * EMB / 8), 256, 0, stream>>>(emb, emb16, VOC * EMB / 8);
        cvt_f32_bf16<<<cvt_grid(EMB * E4 / 8), 256, 0, stream>>>(Whp, Whp16, EMB * E4 / 8);
        cvt_f32_bf16<<<cvt_grid(UDIM * EMB / 8), 256, 0, stream>>>(Wph, Wph16, UDIM * EMB / 8);
        chunkmean_kernel<<<NCHUNK, 256, 0, stream>>>(states, chunk);
        gemm_nt<0><<<dim3(MDIM / 128, SEQ / 128), 256, 0, stream>>>(states, Wq, bq, qk, SEQ, MDIM, HID);
        gemm_nt<0><<<dim3(MDIM / 128, 1), 256, 0, stream>>>(chunk, Wk, bk, mk, NCHUNK, MDIM, HID);
        gemm_head16_k<<<dim3(E4 / 128, SEQ / 128), 256, 0, stream>>>(states, Whf, bhf, head16, E4, HID);
        gemm_b16o16_k<<<dim3(EMB / 128, SEQ / 128), 256, 0, stream>>>(head16, Whp16, bhp, bfeat16, EMB, E4);
        gemm_nt<0><<<dim3(EMB / 128, 1), 256, 0, stream>>>(chunk, Wcv, bcv, cv, NCHUNK, EMB, HID);
        gemm_nt<0><<<dim3(UDIM / 128, 1), 256, 0, stream>>>(cv, Wph, bph, cp, NCHUNK, UDIM, EMB);
        gemm_bt16_k<<<dim3(UDIM / 128, SEQ / 128), 256, 0, stream>>>(bfeat16, Wph16, bph, bp, UDIM, EMB);
        gemm_bt16_k<<<dim3((VOC + 127) / 128, SEQ / 128), 256, 0, stream>>>(bfeat16, emb16, obias, out, VOC, EMB);
        attn_kernel<<<SEQ, 64, 0, stream>>>(qk, mk, attn);
        total_scatter_kernel<<<SEQ, 256, 0, stream>>>(bp, cp, attn, uids, out);
    } else {
        // fallback: round-4/5 serial path
        float* X = wsf + common_off;
        embed_kernel<<<SEQ, 256, 0, stream>>>(ids, emb, X);
        hipMemsetAsync(states, 0xFF, (size_t)SEQ * HID * sizeof(float), stream);
        gemm_nt<0><<<dim3(G3 / 128, SEQ / 128), 256, 0, stream>>>(X, w_ih, b_ih, GX, SEQ, G3, EMB);
        gru_kernel<<<G_GRU, 256, 0, stream>>>(GX, w_hh, b_hh, states);
        chunkmean_kernel<<<NCHUNK, 256, 0, stream>>>(states, chunk);
        gemm_nt<0><<<dim3(MDIM / 128, SEQ / 128), 256, 0, stream>>>(states, Wq, bq, qk, SEQ, MDIM, HID);
        gemm_nt<0><<<dim3(MDIM / 128, 1), 256, 0, stream>>>(chunk, Wk, bk, mk, NCHUNK, MDIM, HID);
        gemm_nt<1><<<dim3(E4 / 128, SEQ / 128), 256, 0, stream>>>(states, Whf, bhf, head, SEQ, E4, HID);
        gemm_nt<0><<<dim3(EMB / 128, SEQ / 128), 256, 0, stream>>>(head, Whp, bhp, bfeat, SEQ, EMB, E4);
        gemm_nt<0><<<dim3(EMB / 128, 1), 256, 0, stream>>>(chunk, Wcv, bcv, cv, NCHUNK, EMB, HID);
        gemm_nt<0><<<dim3(UDIM / 128, 1), 256, 0, stream>>>(cv, Wph, bph, cp, NCHUNK, UDIM, EMB);
        gemm_nt<0><<<dim3(UDIM / 128, SEQ / 128), 256, 0, stream>>>(bfeat, Wph, bph, bp, SEQ, UDIM, EMB);
        gemm_bf16_logits<<<dim3((VOC + 127) / 128, SEQ / 128), 256, 0, stream>>>(bfeat, emb, obias, out, VOC, EMB);
        attn_kernel<<<SEQ, 64, 0, stream>>>(qk, mk, attn);
        total_scatter_kernel<<<SEQ, 256, 0, stream>>>(bp, cp, attn, uids, out);
    }
}